// Round 5
// baseline (260.942 us; speedup 1.0000x reference)
//
#include <hip/hip_runtime.h>
#include <math.h>

// [B=2, 1, D=192, H=192, W=192] fp32
#define W 192
#define H 192
#define DEPTH 192
#define BATCH 2
#define TW 64
#define TH 8
#define DC 12                 // output planes per block -> grid 72*16*2 = 2304
#define HW (H * W)
#define VOL ((size_t)DEPTH * HW)
#define ROUNDS (DC + 2)       // 14 single-plane rounds: planes d0-1 .. d0+12
#define LROW 72               // raw halo row [w0-4, w0+68)
#define LPL (10 * LROW)       // one array-plane: 10 rows
#define NUNIT 360             // staging float4 units per plane: 2 arrays * 10 rows * 18

// Round t: [ds_write X(plane t)->buf[t&1]; ONE barrier; issue loads(plane t+1);
//           compute plane t]. Loads get a full round of slack; the only VMEM
// in flight at each barrier is the tiny ctr prefetch -> cheap vmcnt drain.

__global__ __launch_bounds__(256) void sobel_loss_part(
    const float* __restrict__ pred, const float* __restrict__ gt,
    const float* __restrict__ mask, float* __restrict__ partials)
{
    __shared__ __align__(16) float lds[2 * 2 * LPL];   // [buf][array][10*72] = 11.5 KB

    const int tid = threadIdx.x;
    const int tx = blockIdx.x % 3, ty = blockIdx.x / 3;
    const int w0 = tx * TW, h0 = ty * TH;
    const int d0 = blockIdx.y * DC;
    const size_t base = (size_t)blockIdx.z * VOL;

    // compute mapping: 1 row x 2 adjacent cols
    const int wy  = tid >> 5;
    const int wxo = (tid & 31) << 1;
    const int ctr_off = (h0 + wy) * W + (w0 + wxo);

    // ---- staging geometry (loop-invariant): u = tid + 256k, u < 360 ----
    // a = u/180 (0=pred,1=gt), r = (u%180)/18 row 0..9, cg = col4-group 0..17
    int s_ld[2], s_go[2], s_a[2];
    bool s_row[2];
    #pragma unroll
    for (int k = 0; k < 2; ++k) {
        int u = tid + 256 * k;
        int uu = (u < NUNIT) ? u : 0;
        int a = uu / 180; int rem = uu - a * 180;
        int r = rem / 18; int cg = rem - r * 18;
        int y = h0 - 1 + r;
        int x = w0 - 4 + 4 * cg;          // 16B aligned; OOB float4 fully OOB
        bool rok = (u < NUNIT) && ((unsigned)y < (unsigned)H) && ((unsigned)x < (unsigned)W);
        s_row[k] = rok;
        s_go[k]  = rok ? (y * W + x) : 0;
        s_ld[k]  = (a * 10 + r) * LROW + 4 * cg;
        s_a[k]   = a;
    }

    float4 X[2];
    auto load_plane = [&](int p) {
        const bool pv = (p >= 0) && (p < DEPTH);
        const size_t pb = base + (size_t)(pv ? p : 0) * HW;
        #pragma unroll
        for (int k = 0; k < 2; ++k) {
            const bool ok = pv && s_row[k];
            const float* sp = (s_a[k] ? gt : pred) + pb + s_go[k];
            X[k] = ok ? *(const float4*)sp : make_float4(0.f, 0.f, 0.f, 0.f);
        }
    };

    float2 Mn = {0,0}, Pn = {0,0}, Gn = {0,0};
    auto load_ctr = [&](int od) {       // centers+mask for output plane od
        const size_t o = base + (size_t)od * HW + ctr_off;
        Mn = *(const float2*)(mask + o);
        Pn = *(const float2*)(pred + o);
        Gn = *(const float2*)(gt   + o);
    };

    // 3-deep D-history [array][col][slot], rotated by compile-time t%3
    float hdx[2][2][3], hsx[2][2][3], hdy[2][2][3];
    #pragma unroll
    for (int a = 0; a < 2; ++a)
        #pragma unroll
        for (int o = 0; o < 2; ++o)
            #pragma unroll
            for (int j = 0; j < 3; ++j) { hdx[a][o][j]=0.f; hsx[a][o][j]=0.f; hdy[a][o][j]=0.f; }
    float acc = 0.f;
    float2 Mc, Pc, Gc;

    load_plane(d0 - 1);                 // prefetch round 0

    #pragma unroll
    for (int t = 0; t < ROUNDS; ++t) {
        const int buf = t & 1;
        // stage prefetched plane (vmcnt wait here: loads had a full round)
        *(float4*)(lds + buf * 2 * LPL + s_ld[0]) = X[0];
        if (tid < NUNIT - 256)
            *(float4*)(lds + buf * 2 * LPL + s_ld[1]) = X[1];
        __syncthreads();                // the ONLY barrier per round

        if (t + 1 < ROUNDS) load_plane(d0 + t);     // plane d0-1+(t+1)
        Mc = Mn; Pc = Pn; Gc = Gn;
        if (t >= 1 && t <= DC) load_ctr(d0 + t - 1); // consumed at round t+1

        const int wsl = t % 3;          // slot for plane p = d0-1+t
        const int i0  = (t + 1) % 3;    // plane p-2
        const int i1  = (t + 2) % 3;    // plane p-1

        #pragma unroll
        for (int a = 0; a < 2; ++a) {
            const float* R = lds + (buf * 2 + a) * LPL + wy * LROW + (wxo + 2);
            float2 v00 = *(const float2*)(R),            v01 = *(const float2*)(R + 2),            v02 = *(const float2*)(R + 4);
            float2 v10 = *(const float2*)(R + LROW),     v11 = *(const float2*)(R + LROW + 2),     v12 = *(const float2*)(R + LROW + 4);
            float2 v20 = *(const float2*)(R + 2*LROW),   v21 = *(const float2*)(R + 2*LROW + 2),   v22 = *(const float2*)(R + 2*LROW + 4);
            #pragma unroll
            for (int o = 0; o < 2; ++o) {
                float sh0 = o ? (v01.x + 2.f*v01.y + v02.x) : (v00.y + 2.f*v01.x + v01.y);
                float dh0 = o ? (v02.x - v01.x)             : (v01.y - v00.y);
                float sh1 = o ? (v11.x + 2.f*v11.y + v12.x) : (v10.y + 2.f*v11.x + v11.y);
                float dh1 = o ? (v12.x - v11.x)             : (v11.y - v10.y);
                float sh2 = o ? (v21.x + 2.f*v21.y + v22.x) : (v20.y + 2.f*v21.x + v21.y);
                float dh2 = o ? (v22.x - v21.x)             : (v21.y - v20.y);
                hdx[a][o][wsl] = dh0 + 2.f * dh1 + dh2;
                hsx[a][o][wsl] = sh0 + 2.f * sh1 + sh2;
                hdy[a][o][wsl] = sh0 - sh2;
            }
        }

        if (t >= 2) {                   // output plane od = d0+t-2; ctr from round t-1
            #pragma unroll
            for (int o = 0; o < 2; ++o) {
                float gx = hdx[0][o][i0] + 2.f * hdx[0][o][i1] + hdx[0][o][wsl];
                float gy = hdy[0][o][i0] + 2.f * hdy[0][o][i1] + hdy[0][o][wsl];
                float gz = hsx[0][o][i0] - hsx[0][o][wsl];
                float ga = __builtin_amdgcn_sqrtf(fmaf(gz, gz, fmaf(gy, gy, fmaf(gx, gx, 1e-10f))));
                float hx = hdx[1][o][i0] + 2.f * hdx[1][o][i1] + hdx[1][o][wsl];
                float hy = hdy[1][o][i0] + 2.f * hdy[1][o][i1] + hdy[1][o][wsl];
                float hz = hsx[1][o][i0] - hsx[1][o][wsl];
                float gb = __builtin_amdgcn_sqrtf(fmaf(hz, hz, fmaf(hy, hy, fmaf(hx, hx, 1e-10f))));
                float m  = o ? Mc.y : Mc.x;
                float dm = (o ? Pc.y : Pc.x) - (o ? Gc.y : Gc.x);
                float mse = dm * dm * m;
                float dg  = gb - ga;
                float mge = dg * dg * m;
                // 1 + tanh(x) = 2 - 2*rcp(e^{2x}+1), x >= 0; saturates via inf->rcp->0
                float ex = __expf(mge + mge);
                float rc = __builtin_amdgcn_rcpf(ex + 1.f);
                acc = fmaf(mse, fmaf(-2.f, rc, 2.f), acc);
            }
        }
    }

    // block reduction
    float v = acc;
    #pragma unroll
    for (int o = 32; o > 0; o >>= 1) v += __shfl_down(v, o, 64);
    __shared__ float red[4];
    if ((tid & 63) == 0) red[tid >> 6] = v;
    __syncthreads();
    if (tid == 0) {
        partials[(size_t)blockIdx.z * (gridDim.x * gridDim.y)
                 + (size_t)blockIdx.y * gridDim.x + blockIdx.x]
            = red[0] + red[1] + red[2] + red[3];
    }
}

__global__ __launch_bounds__(256) void reduce_final(
    const float* __restrict__ partials, int n, float* __restrict__ out)
{
    int tid = threadIdx.x;
    double s = 0.0;
    for (int i = tid; i < n; i += 256) s += (double)partials[i];
    #pragma unroll
    for (int o = 32; o > 0; o >>= 1) s += __shfl_down(s, o, 64);
    __shared__ double red[4];
    if ((tid & 63) == 0) red[tid >> 6] = s;
    __syncthreads();
    if (tid == 0) {
        double t = red[0] + red[1] + red[2] + red[3];
        const double ntot = (double)BATCH * (double)DEPTH * (double)H * (double)W;
        out[0] = (float)(t / ntot);
    }
}

extern "C" void kernel_launch(void* const* d_in, const int* in_sizes, int n_in,
                              void* d_out, int out_size, void* d_ws, size_t ws_size,
                              hipStream_t stream) {
    const float* pred = (const float*)d_in[0];
    const float* gt   = (const float*)d_in[1];
    const float* mask = (const float*)d_in[2];
    float* partials = (float*)d_ws;

    dim3 grid((W / TW) * (H / TH), DEPTH / DC, BATCH);   // 72 x 16 x 2 = 2304
    sobel_loss_part<<<grid, 256, 0, stream>>>(pred, gt, mask, partials);

    int nparts = grid.x * grid.y * grid.z;
    reduce_final<<<1, 256, 0, stream>>>(partials, nparts, (float*)d_out);
}

// Round 6
// 215.709 us; speedup vs baseline: 1.2097x; 1.2097x over previous
//
#include <hip/hip_runtime.h>
#include <math.h>

// [B=2, 1, D=192, H=192, W=192] fp32
#define W 192
#define H 192
#define DEPTH 192
#define BATCH 2
#define DC 12                  // output planes per block-chunk
#define HW (H * W)
#define VOL ((size_t)DEPTH * HW)
#define ROWT 48                // threads per H-row, 4 cols each -> full W
#define ROWSB 4                // H-rows per block
#define BLOCKT (ROWT * ROWSB)  // 192 threads = 3 waves
#define ROUNDS (DC + 2)        // planes d0-1 .. d0+DC

// No-LDS, no-barrier streaming 2.5D stencil.
// Thread = 4 W-cols x 1 H-row, marching DC planes in D.
// Per plane, per array: 3 rows x (scalar, float4, scalar) global loads (L1-hot
// for H-shared rows). W+H Sobel combine in registers; D combine via 2-deep
// pending accumulators (no rotating history, no %3, loop stays rolled).
// Loop body has no stores/barriers -> compiler pipelines loads across iters.

__global__ __launch_bounds__(BLOCKT, 3) void sobel_loss_part(
    const float* __restrict__ pred, const float* __restrict__ gt,
    const float* __restrict__ mask, float* __restrict__ partials)
{
    const int tid = threadIdx.x;
    const int rt = tid / ROWT;          // row in block 0..3
    const int ct = tid - rt * ROWT;     // col group 0..47
    const int wc = 4 * ct;
    const int h  = blockIdx.x * ROWSB + rt;
    const int d0 = blockIdx.y * DC;
    const size_t base = (size_t)blockIdx.z * VOL;

    const bool lok = (wc > 0);
    const bool rok = (wc + 4 < W);
    const bool y0ok = (h > 0);
    const bool y2ok = (h + 1 < H);
    const int g1 = h * W + wc;          // middle row, within-plane offset
    const int g0 = g1 - W, g2 = g1 + W;

    // pending D-combine accumulators [array][col]
    float AX[2][4], BX[2][4], AY[2][4], BY[2][4], AZ[2][4], BZ[2][4];
    #pragma unroll
    for (int a = 0; a < 2; ++a)
        #pragma unroll
        for (int c = 0; c < 4; ++c) {
            AX[a][c]=BX[a][c]=AY[a][c]=BY[a][c]=AZ[a][c]=BZ[a][c]=0.f;
        }

    float Pc[4] = {0,0,0,0}, Gc[4] = {0,0,0,0};   // centers of plane p-1
    float acc = 0.f;

    #pragma unroll 2
    for (int t = 0; t < ROUNDS; ++t) {
        const int p = d0 - 1 + t;
        const bool pv = (p >= 0) && (p < DEPTH);
        const size_t pb = base + (size_t)(pv ? p : 0) * HW;

        float outx[2][4], outy[2][4], outz[2][4];
        float mid[2][4];

        #pragma unroll
        for (int a = 0; a < 2; ++a) {
            const float* __restrict__ src = a ? gt : pred;
            const bool r0 = pv && y0ok, r1 = pv, r2 = pv && y2ok;
            float4 m0 = r0 ? *(const float4*)(src + pb + g0) : make_float4(0,0,0,0);
            float4 m1 = r1 ? *(const float4*)(src + pb + g1) : make_float4(0,0,0,0);
            float4 m2 = r2 ? *(const float4*)(src + pb + g2) : make_float4(0,0,0,0);
            float v[3][6];
            v[0][0] = (r0 && lok) ? src[pb + g0 - 1] : 0.f;
            v[0][5] = (r0 && rok) ? src[pb + g0 + 4] : 0.f;
            v[1][0] = (r1 && lok) ? src[pb + g1 - 1] : 0.f;
            v[1][5] = (r1 && rok) ? src[pb + g1 + 4] : 0.f;
            v[2][0] = (r2 && lok) ? src[pb + g2 - 1] : 0.f;
            v[2][5] = (r2 && rok) ? src[pb + g2 + 4] : 0.f;
            v[0][1]=m0.x; v[0][2]=m0.y; v[0][3]=m0.z; v[0][4]=m0.w;
            v[1][1]=m1.x; v[1][2]=m1.y; v[1][3]=m1.z; v[1][4]=m1.w;
            v[2][1]=m2.x; v[2][2]=m2.y; v[2][3]=m2.z; v[2][4]=m2.w;
            mid[a][0]=m1.x; mid[a][1]=m1.y; mid[a][2]=m1.z; mid[a][3]=m1.w;

            float sh[3][4], dh[3][4];
            #pragma unroll
            for (int r = 0; r < 3; ++r)
                #pragma unroll
                for (int c = 0; c < 4; ++c) {
                    sh[r][c] = v[r][c] + 2.f * v[r][c+1] + v[r][c+2];
                    dh[r][c] = v[r][c+2] - v[r][c];
                }
            #pragma unroll
            for (int c = 0; c < 4; ++c) {
                float qdx = dh[0][c] + 2.f * dh[1][c] + dh[2][c];  // s_h d_w
                float qsx = sh[0][c] + 2.f * sh[1][c] + sh[2][c];  // s_h s_w
                float qdy = sh[0][c] - sh[2][c];                   // d_h s_w
                outx[a][c] = AX[a][c] + qdx;             // gx(p-1) complete
                AX[a][c]   = fmaf(2.f, qdx, BX[a][c]);
                BX[a][c]   = qdx;
                outy[a][c] = AY[a][c] + qdy;             // gy(p-1)
                AY[a][c]   = fmaf(2.f, qdy, BY[a][c]);
                BY[a][c]   = qdy;
                outz[a][c] = AZ[a][c] - qsx;             // gz(p-1)=asx(p-2)-asx(p)
                AZ[a][c]   = BZ[a][c];
                BZ[a][c]   = qsx;
            }
        }

        if (t >= 2) {                   // output plane od = p-1 (d0 .. d0+DC-1)
            const int od = p - 1;
            const float4 M4 = *(const float4*)(mask + base + (size_t)od * HW + g1);
            const float mv[4] = {M4.x, M4.y, M4.z, M4.w};
            #pragma unroll
            for (int c = 0; c < 4; ++c) {
                float ga = __builtin_amdgcn_sqrtf(
                    fmaf(outz[0][c], outz[0][c],
                    fmaf(outy[0][c], outy[0][c],
                    fmaf(outx[0][c], outx[0][c], 1e-10f))));
                float gb = __builtin_amdgcn_sqrtf(
                    fmaf(outz[1][c], outz[1][c],
                    fmaf(outy[1][c], outy[1][c],
                    fmaf(outx[1][c], outx[1][c], 1e-10f))));
                float m   = mv[c];
                float dm  = Pc[c] - Gc[c];
                float mse = dm * dm * m;
                float dg  = gb - ga;
                float mge = dg * dg * m;
                // 1 + tanh(x) = 2 - 2*rcp(e^{2x}+1), x >= 0; saturates inf->rcp->0
                float ex = __expf(mge + mge);
                float rc = __builtin_amdgcn_rcpf(ex + 1.f);
                acc = fmaf(mse, fmaf(-2.f, rc, 2.f), acc);
            }
        }
        #pragma unroll
        for (int c = 0; c < 4; ++c) { Pc[c] = mid[0][c]; Gc[c] = mid[1][c]; }
    }

    // block reduction: 3 waves
    float v = acc;
    #pragma unroll
    for (int o = 32; o > 0; o >>= 1) v += __shfl_down(v, o, 64);
    __shared__ float red[3];
    if ((tid & 63) == 0) red[tid >> 6] = v;
    __syncthreads();
    if (tid == 0) {
        partials[(size_t)blockIdx.z * (gridDim.x * gridDim.y)
                 + (size_t)blockIdx.y * gridDim.x + blockIdx.x]
            = red[0] + red[1] + red[2];
    }
}

__global__ __launch_bounds__(256) void reduce_final(
    const float* __restrict__ partials, int n, float* __restrict__ out)
{
    int tid = threadIdx.x;
    double s = 0.0;
    for (int i = tid; i < n; i += 256) s += (double)partials[i];
    #pragma unroll
    for (int o = 32; o > 0; o >>= 1) s += __shfl_down(s, o, 64);
    __shared__ double red[4];
    if ((tid & 63) == 0) red[tid >> 6] = s;
    __syncthreads();
    if (tid == 0) {
        double t = red[0] + red[1] + red[2] + red[3];
        const double ntot = (double)BATCH * (double)DEPTH * (double)H * (double)W;
        out[0] = (float)(t / ntot);
    }
}

extern "C" void kernel_launch(void* const* d_in, const int* in_sizes, int n_in,
                              void* d_out, int out_size, void* d_ws, size_t ws_size,
                              hipStream_t stream) {
    const float* pred = (const float*)d_in[0];
    const float* gt   = (const float*)d_in[1];
    const float* mask = (const float*)d_in[2];
    float* partials = (float*)d_ws;

    dim3 grid(H / ROWSB, DEPTH / DC, BATCH);   // 48 x 16 x 2 = 1536 blocks
    sobel_loss_part<<<grid, BLOCKT, 0, stream>>>(pred, gt, mask, partials);

    int nparts = grid.x * grid.y * grid.z;
    reduce_final<<<1, 256, 0, stream>>>(partials, nparts, (float*)d_out);
}